// Round 4
// baseline (203.138 us; speedup 1.0000x reference)
//
#include <hip/hip_runtime.h>
#include <hip/hip_bf16.h>

#define BCNT 128
#define NNODE 64
#define HDIM 256
#define DDIM 128
#define KNEI 8
#define NR (BCNT * NNODE)   // 8192 rows

typedef __attribute__((ext_vector_type(8))) short bf16x8;
typedef __attribute__((ext_vector_type(8))) unsigned short ushort8;
typedef __attribute__((ext_vector_type(16))) float f32x16;

__device__ __forceinline__ unsigned short f2bf(float f) {
    union { __hip_bfloat16 b; unsigned short u; } c;
    c.b = __float2bfloat16(f);
    return c.u;
}
__device__ __forceinline__ float bf2f(unsigned short u) {
    union { unsigned short u; __hip_bfloat16 b; } c;
    c.u = u;
    return __bfloat162float(c.b);
}

// ---------------------------------------------------------------------------
// xsplit: obs/act f32 -> bf16 hi/lo planes (Markidis pre-split, done once)
// ---------------------------------------------------------------------------
__global__ __launch_bounds__(256) void xsplit(
    const float* __restrict__ obs, const float* __restrict__ act,
    ushort* __restrict__ obsH, ushort* __restrict__ obsL,
    ushort* __restrict__ actH, ushort* __restrict__ actL)
{
    size_t i = ((size_t)blockIdx.x * 256 + threadIdx.x) * 4;
    const size_t NT = (size_t)NR * HDIM;
    const float* src; ushort *dh, *dl;
    if (i < NT) { src = obs; dh = obsH; dl = obsL; }
    else        { i -= NT; src = act; dh = actH; dl = actL; }
    float4 v = *(const float4*)(src + i);
    ushort4 h4, l4;
    h4.x = f2bf(v.x); l4.x = f2bf(v.x - bf2f(h4.x));
    h4.y = f2bf(v.y); l4.y = f2bf(v.y - bf2f(h4.y));
    h4.z = f2bf(v.z); l4.z = f2bf(v.z - bf2f(h4.z));
    h4.w = f2bf(v.w); l4.w = f2bf(v.w - bf2f(h4.w));
    *(ushort4*)(dh + i) = h4;
    *(ushort4*)(dl + i) = l4;
}

// ---------------------------------------------------------------------------
// mlp1: h = X @ W1 + b1 (pre-LN f32) + partial LN stats.
// Block 32 rows x 64 outs, 2 waves (each 32x32 MFMA tile), 128 thr.
// X staged from pre-split bf16 planes (pure copy); W split in-reg, prefetched.
// Grid 1024 linear, XCD-swizzled: 4 bm-siblings share W panel on one XCD.
// ---------------------------------------------------------------------------
template<int KDIM>
__global__ __launch_bounds__(128) void mlp1_mfma(
    const ushort* __restrict__ obsH, const ushort* __restrict__ obsL,
    const ushort* __restrict__ actH, const ushort* __restrict__ actL,
    const float* __restrict__ W1, const float* __restrict__ b1,
    float* __restrict__ h, float* __restrict__ statsP)
{
    const int id = blockIdx.x;
    const int s_ = (id >> 3) & 3;                 // sibling (bm)
    const int g_ = ((id >> 5) << 3) | (id & 7);   // group 0..255, same XCD for sibs
    const int n  = g_ >> 2;
    const int cb = g_ & 3;
    const int bm = s_ * 32;

    const int tid = threadIdx.x;
    const int l = tid & 63;
    const int wc = tid >> 6;                      // col-tile 0..1
    const int lo32 = l & 31, gg = l >> 5;

    __shared__ __align__(16) ushort xs[2][2][32 * 40];  // [dbuf][hi/lo][row*40]
    __shared__ float sstat[2][32][2];

    const int oW = cb * 64 + wc * 32 + lo32;
    const float* wp = W1 + (size_t)n * KDIM * HDIM + oW;

    const int sm = tid >> 2, sc = tid & 3;
    const size_t xrow = ((size_t)(bm + sm) * NNODE + n) * HDIM;

    f32x16 acc = {};
    ushort8 xh, xl;
    float wvA_[16], wvB_[16];

    auto loadX = [&](int k0) {
        const ushort *sh = obsH, *sl = obsL;
        int kk = k0;
        if (KDIM == 512 && k0 >= 256) { sh = actH; sl = actL; kk = k0 - 256; }
        xh = *(const ushort8*)(sh + xrow + kk + sc * 8);
        xl = *(const ushort8*)(sl + xrow + kk + sc * 8);
    };

#define LOADW1(k0, wv) { _Pragma("unroll") for (int kb = 0; kb < 2; ++kb) { _Pragma("unroll") for (int i = 0; i < 8; ++i) wv[kb*8+i] = wp[(size_t)((k0) + kb*16 + gg*8 + i) * HDIM]; } }

#define STEP1(k0, buf, wvC, wvN) { \
    *(ushort8*)&xs[buf][0][sm * 40 + sc * 8] = xh; \
    *(ushort8*)&xs[buf][1][sm * 40 + sc * 8] = xl; \
    __syncthreads(); \
    if ((k0) + 32 < KDIM) { loadX((k0) + 32); LOADW1((k0) + 32, wvN); } \
    _Pragma("unroll") for (int kb = 0; kb < 2; ++kb) { \
        bf16x8 ahi = *(const bf16x8*)&xs[buf][0][lo32 * 40 + kb * 16 + gg * 8]; \
        bf16x8 alo = *(const bf16x8*)&xs[buf][1][lo32 * 40 + kb * 16 + gg * 8]; \
        bf16x8 bhi, blo; \
        _Pragma("unroll") for (int i = 0; i < 8; ++i) { \
            float f = wvC[kb*8+i]; \
            unsigned short hh = f2bf(f); \
            bhi[i] = (short)hh; \
            blo[i] = (short)f2bf(f - bf2f(hh)); \
        } \
        acc = __builtin_amdgcn_mfma_f32_32x32x16_bf16(ahi, bhi, acc, 0, 0, 0); \
        acc = __builtin_amdgcn_mfma_f32_32x32x16_bf16(ahi, blo, acc, 0, 0, 0); \
        acc = __builtin_amdgcn_mfma_f32_32x32x16_bf16(alo, bhi, acc, 0, 0, 0); \
    } \
}

    loadX(0);
    LOADW1(0, wvA_);
    #pragma unroll
    for (int k0 = 0; k0 < KDIM; k0 += 64) {
        STEP1(k0, 0, wvA_, wvB_);
        STEP1(k0 + 32, 1, wvB_, wvA_);
    }
#undef STEP1
#undef LOADW1

    float bias = b1[(size_t)n * HDIM + oW];
    #pragma unroll
    for (int r = 0; r < 16; ++r) {
        int mm = (r & 3) + 8 * (r >> 2) + 4 * gg;
        float v = acc[r] + bias;
        h[((size_t)(bm + mm) * NNODE + n) * HDIM + oW] = v;
        float a = v, q = v * v;
        #pragma unroll
        for (int off = 16; off >= 1; off >>= 1) {
            a += __shfl_xor(a, off);
            q += __shfl_xor(q, off);
        }
        if (lo32 == 0) { sstat[wc][mm][0] = a; sstat[wc][mm][1] = q; }
    }
    __syncthreads();
    if (tid < 32) {
        float s1 = sstat[0][tid][0] + sstat[1][tid][0];
        float s2 = sstat[0][tid][1] + sstat[1][tid][1];
        size_t row = (size_t)(bm + tid) * NNODE + n;
        statsP[((size_t)cb * NR + row) * 2 + 0] = s1;
        statsP[((size_t)cb * NR + row) * 2 + 1] = s2;
    }
}

// ---------------------------------------------------------------------------
// lnsplit: finalize stats + LN + ReLU + bf16 hi/lo split, both branches.
// grid (NR/4, 2), 256 thr; thread = 4 cols of one row.
// ---------------------------------------------------------------------------
__global__ __launch_bounds__(256) void lnsplit(
    const float* __restrict__ hV, const float* __restrict__ hA,
    const float* __restrict__ stV, const float* __restrict__ stA,
    const float* __restrict__ Vg1, const float* __restrict__ Vbe1,
    const float* __restrict__ Ag1, const float* __restrict__ Abe1,
    ushort* __restrict__ hbVH, ushort* __restrict__ hbVL,
    ushort* __restrict__ hbAH, ushort* __restrict__ hbAL)
{
    const int br = blockIdx.y;
    const float* hp = br ? hA : hV;
    const float* st = br ? stA : stV;
    const float* gp = br ? Ag1 : Vg1;
    const float* bp = br ? Abe1 : Vbe1;
    ushort* oh = br ? hbAH : hbVH;
    ushort* ol = br ? hbAL : hbVL;

    const int tid = threadIdx.x;
    const int row = blockIdx.x * 4 + (tid >> 6);
    const int c4 = (tid & 63) * 4;

    float s1 = 0.f, s2 = 0.f;
    #pragma unroll
    for (int cb = 0; cb < 4; ++cb) {
        s1 += st[((size_t)cb * NR + row) * 2 + 0];
        s2 += st[((size_t)cb * NR + row) * 2 + 1];
    }
    float mu = s1 * (1.0f / 256.0f);
    float rs = rsqrtf(s2 * (1.0f / 256.0f) - mu * mu + 1e-5f);

    float4 v = *(const float4*)(hp + (size_t)row * HDIM + c4);
    float4 gv = *(const float4*)(gp + c4);
    float4 bv = *(const float4*)(bp + c4);
    float y0 = fmaxf((v.x - mu) * rs * gv.x + bv.x, 0.0f);
    float y1 = fmaxf((v.y - mu) * rs * gv.y + bv.y, 0.0f);
    float y2 = fmaxf((v.z - mu) * rs * gv.z + bv.z, 0.0f);
    float y3 = fmaxf((v.w - mu) * rs * gv.w + bv.w, 0.0f);
    ushort4 h4, l4;
    h4.x = f2bf(y0); l4.x = f2bf(y0 - bf2f(h4.x));
    h4.y = f2bf(y1); l4.y = f2bf(y1 - bf2f(h4.y));
    h4.z = f2bf(y2); l4.z = f2bf(y2 - bf2f(h4.z));
    h4.w = f2bf(y3); l4.w = f2bf(y3 - bf2f(h4.w));
    *(ushort4*)(oh + (size_t)row * HDIM + c4) = h4;
    *(ushort4*)(ol + (size_t)row * HDIM + c4) = l4;
}

// ---------------------------------------------------------------------------
// mlp2: branch br==0: V = ln(hV)relu @ VW2 + Vb2 ; br==1: A-part likewise.
// Same tile/pipeline as mlp1; K=256; outs 128 (cb 0..1). Q formed in chi.
// ---------------------------------------------------------------------------
__global__ __launch_bounds__(128) void mlp2_mfma(
    const ushort* __restrict__ hbVH, const ushort* __restrict__ hbVL,
    const ushort* __restrict__ hbAH, const ushort* __restrict__ hbAL,
    const float* __restrict__ VW2, const float* __restrict__ Vb2,
    const float* __restrict__ AW2, const float* __restrict__ Ab2,
    float* __restrict__ Vout, float* __restrict__ Aout)
{
    const int id = blockIdx.x;
    const int s_ = (id >> 3) & 3;
    const int g_ = ((id >> 5) << 3) | (id & 7);
    const int n  = g_ >> 2;
    const int cb = g_ & 1;
    const int br = (g_ >> 1) & 1;
    const int bm = s_ * 32;

    const int tid = threadIdx.x;
    const int l = tid & 63;
    const int wc = tid >> 6;
    const int lo32 = l & 31, gg = l >> 5;

    __shared__ __align__(16) ushort xs[2][2][32 * 40];

    const int oW = cb * 64 + wc * 32 + lo32;
    const float* wp = (br ? AW2 : VW2) + (size_t)n * HDIM * DDIM + oW;
    const ushort* xph = br ? hbAH : hbVH;
    const ushort* xpl = br ? hbAL : hbVL;

    const int sm = tid >> 2, sc = tid & 3;
    const size_t xrow = ((size_t)(bm + sm) * NNODE + n) * HDIM;

    f32x16 acc = {};
    ushort8 xh, xl;
    float wvA_[16], wvB_[16];

    auto loadX = [&](int k0) {
        xh = *(const ushort8*)(xph + xrow + k0 + sc * 8);
        xl = *(const ushort8*)(xpl + xrow + k0 + sc * 8);
    };

#define LOADW2(k0, wv) { _Pragma("unroll") for (int kb = 0; kb < 2; ++kb) { _Pragma("unroll") for (int i = 0; i < 8; ++i) wv[kb*8+i] = wp[(size_t)((k0) + kb*16 + gg*8 + i) * DDIM]; } }

#define STEP2(k0, buf, wvC, wvN) { \
    *(ushort8*)&xs[buf][0][sm * 40 + sc * 8] = xh; \
    *(ushort8*)&xs[buf][1][sm * 40 + sc * 8] = xl; \
    __syncthreads(); \
    if ((k0) + 32 < HDIM) { loadX((k0) + 32); LOADW2((k0) + 32, wvN); } \
    _Pragma("unroll") for (int kb = 0; kb < 2; ++kb) { \
        bf16x8 ahi = *(const bf16x8*)&xs[buf][0][lo32 * 40 + kb * 16 + gg * 8]; \
        bf16x8 alo = *(const bf16x8*)&xs[buf][1][lo32 * 40 + kb * 16 + gg * 8]; \
        bf16x8 bhi, blo; \
        _Pragma("unroll") for (int i = 0; i < 8; ++i) { \
            float f = wvC[kb*8+i]; \
            unsigned short hh = f2bf(f); \
            bhi[i] = (short)hh; \
            blo[i] = (short)f2bf(f - bf2f(hh)); \
        } \
        acc = __builtin_amdgcn_mfma_f32_32x32x16_bf16(ahi, bhi, acc, 0, 0, 0); \
        acc = __builtin_amdgcn_mfma_f32_32x32x16_bf16(ahi, blo, acc, 0, 0, 0); \
        acc = __builtin_amdgcn_mfma_f32_32x32x16_bf16(alo, bhi, acc, 0, 0, 0); \
    } \
}

    loadX(0);
    LOADW2(0, wvA_);
    #pragma unroll
    for (int k0 = 0; k0 < HDIM; k0 += 64) {
        STEP2(k0, 0, wvA_, wvB_);
        STEP2(k0 + 32, 1, wvB_, wvA_);
    }
#undef STEP2
#undef LOADW2

    float bias = (br ? Ab2 : Vb2)[(size_t)n * DDIM + oW];
    float* outp = br ? Aout : Vout;
    #pragma unroll
    for (int r = 0; r < 16; ++r) {
        int mm = (r & 3) + 8 * (r >> 2) + 4 * gg;
        outp[((size_t)(bm + mm) * NNODE + n) * DDIM + oW] = acc[r] + bias;
    }
}

// ---------------------------------------------------------------------------
// chi for both Q=V+A and V; one block per (n, b), 128 threads = one per d
// ---------------------------------------------------------------------------
__global__ __launch_bounds__(128) void chi_kernel(
    const float* __restrict__ V, const float* __restrict__ A,
    const int* __restrict__ le, const float* __restrict__ m1,
    const float* __restrict__ m2, float* __restrict__ out)
{
    const int n = blockIdx.x;
    const int b = blockIdx.y;
    const int tid = threadIdx.x;

    __shared__ float sm1[KNEI];
    __shared__ float sm2[KNEI * KNEI];
    __shared__ int   sidx[KNEI + 1];
    __shared__ float pq[2], pv[2];

    if (tid < KNEI) {
        float s = 0.0f;
        #pragma unroll
        for (int hh = 0; hh < 3; ++hh) s += m1[n * 24 + hh * 8 + tid];
        sm1[tid] = s;
    }
    if (tid < 64) {
        int i = tid >> 3, j = tid & 7;
        float s = 0.0f;
        if (j > i) {
            #pragma unroll
            for (int hh = 0; hh < 3; ++hh) s += m2[n * 192 + hh * 64 + tid];
        }
        sm2[tid] = s;
    }
    if (tid < KNEI + 1) sidx[tid] = le[n * 18 + tid];
    __syncthreads();

    const float* Vb_ = V + (size_t)b * (NNODE * DDIM);
    const float* Ab_ = A + (size_t)b * (NNODE * DDIM);
    const int cen = sidx[0];

    float vn[KNEI], qn[KNEI];
    #pragma unroll
    for (int k = 0; k < KNEI; ++k) {
        int nb = sidx[1 + k];
        float vv = Vb_[nb * DDIM + tid];
        float aa = Ab_[nb * DDIM + tid];
        vn[k] = vv;
        qn[k] = vv + aa;
    }

    float sq = 0.0f, sv = 0.0f;
    #pragma unroll
    for (int k = 0; k < KNEI; ++k) { sq += sm1[k] * qn[k]; sv += sm1[k] * vn[k]; }
    #pragma unroll
    for (int i = 0; i < KNEI; ++i) {
        #pragma unroll
        for (int j = i + 1; j < KNEI; ++j) {
            float w = sm2[i * 8 + j];
            sq += w * fminf(qn[i], qn[j]);
            sv += w * fminf(vn[i], vn[j]);
        }
    }

    float Vc = Vb_[cen * DDIM + tid];
    float Ac = Ab_[cen * DDIM + tid];
    float valq = sq * (1.0f / 3.0f) + (Vc + Ac);
    float valv = sv * (1.0f / 3.0f) + Vc;

    #pragma unroll
    for (int o = 32; o; o >>= 1) {
        valq += __shfl_down(valq, o);
        valv += __shfl_down(valv, o);
    }
    if ((tid & 63) == 0) { pq[tid >> 6] = valq; pv[tid >> 6] = valv; }
    __syncthreads();
    if (tid == 0) {
        out[b * NNODE + n]                = (pq[0] + pq[1]) * (1.0f / 128.0f);
        out[BCNT * NNODE + b * NNODE + n] = (pv[0] + pv[1]) * (1.0f / 128.0f);
    }
}

extern "C" void kernel_launch(void* const* d_in, const int* in_sizes, int n_in,
                              void* d_out, int out_size, void* d_ws, size_t ws_size,
                              hipStream_t stream)
{
    const float* obs  = (const float*)d_in[0];
    const float* act  = (const float*)d_in[1];
    const int*   le   = (const int*)  d_in[2];
    const float* VW1  = (const float*)d_in[3];
    const float* Vb1  = (const float*)d_in[4];
    const float* Vg1  = (const float*)d_in[5];
    const float* Vbe1 = (const float*)d_in[6];
    const float* VW2  = (const float*)d_in[7];
    const float* Vb2  = (const float*)d_in[8];
    const float* AW1  = (const float*)d_in[9];
    const float* Ab1  = (const float*)d_in[10];
    const float* Ag1  = (const float*)d_in[11];
    const float* Abe1 = (const float*)d_in[12];
    const float* AW2  = (const float*)d_in[13];
    const float* Ab2  = (const float*)d_in[14];
    const float* m1   = (const float*)d_in[15];
    const float* m2   = (const float*)d_in[16];
    float* out = (float*)d_out;

    float* hV  = (float*)d_ws;                   // NR*256 f32
    float* hA  = hV + (size_t)NR * HDIM;
    float* V   = hA + (size_t)NR * HDIM;         // NR*128
    float* A   = V  + (size_t)NR * DDIM;
    float* stV = A  + (size_t)NR * DDIM;         // 4*NR*2
    float* stA = stV + (size_t)4 * NR * 2;
    ushort* up = (ushort*)(stA + (size_t)4 * NR * 2);
    const size_t P = (size_t)NR * HDIM;          // plane elems
    ushort* obsH = up;          ushort* obsL = obsH + P;
    ushort* actH = obsL + P;    ushort* actL = actH + P;
    ushort* hbVH = actL + P;    ushort* hbVL = hbVH + P;
    ushort* hbAH = hbVL + P;    ushort* hbAL = hbAH + P;

    xsplit<<<dim3(4096), dim3(256), 0, stream>>>(obs, act, obsH, obsL, actH, actL);
    mlp1_mfma<256><<<dim3(1024), dim3(128), 0, stream>>>(obsH, obsL, actH, actL,
                                                         VW1, Vb1, hV, stV);
    mlp1_mfma<512><<<dim3(1024), dim3(128), 0, stream>>>(obsH, obsL, actH, actL,
                                                         AW1, Ab1, hA, stA);
    lnsplit<<<dim3(NR / 4, 2), dim3(256), 0, stream>>>(hV, hA, stV, stA,
                                                       Vg1, Vbe1, Ag1, Abe1,
                                                       hbVH, hbVL, hbAH, hbAL);
    mlp2_mfma<<<dim3(1024), dim3(128), 0, stream>>>(hbVH, hbVL, hbAH, hbAL,
                                                    VW2, Vb2, AW2, Ab2, V, A);
    chi_kernel<<<dim3(NNODE, BCNT), dim3(128), 0, stream>>>(V, A, le, m1, m2, out);
}